// Round 1
// baseline (7351.575 us; speedup 1.0000x reference)
//
#include <hip/hip_runtime.h>
#include <hip/hip_bf16.h>
#include <cstdint>
#include <cstddef>

// ---------------------------------------------------------------------------
// Decoder: 2-layer GRU, B=8192 (=64*128), H=512, ENC=1024, ATOM=64, 49 steps.
// All GEMMs in bf16 MFMA (16x16x32), fp32 accum; gates/softmax in fp32.
// gi0 is a table lookup: G0 = emb @ w_ih0.T + b_ih0 precomputed once.
// ---------------------------------------------------------------------------

typedef __attribute__((ext_vector_type(8))) __bf16 bf16x8;
typedef __attribute__((ext_vector_type(4))) __bf16 bf16x4;
typedef __attribute__((ext_vector_type(4))) float f32x4;

#define B_ROWS 8192
#define HID 512
#define GATE3 1536
#define ATOM 64
#define NSTEP 49

// ---- async global->LDS, 16B per lane, wave-uniform LDS base ----------------
#define GLOAD_LDS16(gp, sp)                                                   \
  __builtin_amdgcn_global_load_lds(                                           \
      (__attribute__((address_space(1))) void*)(gp),                          \
      (__attribute__((address_space(3))) void*)(sp), 16, 0, 0)

// ---------------------------------------------------------------------------
// GEMM: C[M,N] = A[M,K] @ B[N,K]^T   (both row-major, K contiguous)
// mode 0: store bf16 C
// mode 1: v = tanh(acc + bias[col]); col<512 -> H0, else H1 (fp32 + bf16)
// ---------------------------------------------------------------------------
#define BM 128
#define BN 128
#define BK 32

__global__ __launch_bounds__(256) void gemm_bt(
    const __bf16* __restrict__ A, const __bf16* __restrict__ B,
    int M, int N, int K, int mode, const float* __restrict__ bias,
    __bf16* __restrict__ Cb,
    float* __restrict__ H0f, __bf16* __restrict__ H0b,
    float* __restrict__ H1f, __bf16* __restrict__ H1b)
{
    __shared__ __bf16 As[BM * BK];
    __shared__ __bf16 Bs[BN * BK];

    const int tid  = threadIdx.x;
    const int lane = tid & 63;
    const int w    = tid >> 6;       // wave 0..3
    const int wm   = w >> 1, wn = w & 1;
    const int m0   = blockIdx.x * BM;
    const int n0   = blockIdx.y * BN;

    f32x4 acc[4][4] = {};

    // staging: 512 chunks of 16B per tile; thread does chunks i0 and i0+256
    const int i0 = w * 64 + lane;
    const int i1 = i0 + 256;
    const __bf16* Ap0 = A + (size_t)(m0 + (i0 >> 2)) * K + (i0 & 3) * 8;
    const __bf16* Ap1 = A + (size_t)(m0 + (i1 >> 2)) * K + (i1 & 3) * 8;
    const __bf16* Bp0 = B + (size_t)(n0 + (i0 >> 2)) * K + (i0 & 3) * 8;
    const __bf16* Bp1 = B + (size_t)(n0 + (i1 >> 2)) * K + (i1 & 3) * 8;
    __bf16* As0 = As + w * 512;           // wave-uniform LDS bases
    __bf16* As1 = As + 2048 + w * 512;
    __bf16* Bs0 = Bs + w * 512;
    __bf16* Bs1 = Bs + 2048 + w * 512;

    const int mrow = wm * 64 + (lane & 15);
    const int nrow = wn * 64 + (lane & 15);
    const int koff = (lane >> 4) * 8;

    const int kIters = K / BK;
    for (int kt = 0; kt < kIters; ++kt) {
        __syncthreads();                       // prev readers done
        GLOAD_LDS16(Ap0, As0);
        GLOAD_LDS16(Ap1, As1);
        GLOAD_LDS16(Bp0, Bs0);
        GLOAD_LDS16(Bp1, Bs1);
        Ap0 += BK; Ap1 += BK; Bp0 += BK; Bp1 += BK;
        __syncthreads();                       // drains vmcnt before barrier

        bf16x8 af[4], bfr[4];
        #pragma unroll
        for (int f = 0; f < 4; ++f) {
            af[f]  = *(const bf16x8*)&As[(mrow + f * 16) * BK + koff];
            bfr[f] = *(const bf16x8*)&Bs[(nrow + f * 16) * BK + koff];
        }
        #pragma unroll
        for (int mf = 0; mf < 4; ++mf)
            #pragma unroll
            for (int nf = 0; nf < 4; ++nf)
                acc[mf][nf] = __builtin_amdgcn_mfma_f32_16x16x32_bf16(
                    af[mf], bfr[nf], acc[mf][nf], 0, 0, 0);
    }

    // epilogue: C/D layout col = lane&15, row = (lane>>4)*4 + r
    const int colb = n0 + wn * 64 + (lane & 15);
    const int rowb = m0 + wm * 64 + ((lane >> 4) << 2);
    #pragma unroll
    for (int mf = 0; mf < 4; ++mf) {
        #pragma unroll
        for (int nf = 0; nf < 4; ++nf) {
            const int col = colb + nf * 16;
            #pragma unroll
            for (int r = 0; r < 4; ++r) {
                const int row = rowb + mf * 16 + r;
                float v = acc[mf][nf][r];
                if (mode == 0) {
                    Cb[(size_t)row * N + col] = (__bf16)v;
                } else {
                    v = tanhf(v + bias[col]);
                    if (col < HID) {
                        H0f[(size_t)row * HID + col] = v;
                        H0b[(size_t)row * HID + col] = (__bf16)v;
                    } else {
                        H1f[(size_t)row * HID + col - HID] = v;
                        H1b[(size_t)row * HID + col - HID] = (__bf16)v;
                    }
                }
            }
        }
    }
}

// ---------------------------------------------------------------------------
// GRU gate update. gi==null -> layer0 path: gi row = G0[p[row]] (bias folded).
// h updated in place (fp32) + bf16 mirror.
// ---------------------------------------------------------------------------
__device__ inline float sig_(float x) { return 1.f / (1.f + __expf(-x)); }
__device__ inline float tanh_(float x) { return 2.f / (1.f + __expf(-2.f * x)) - 1.f; }

__global__ __launch_bounds__(256) void gru_gate(
    const __bf16* __restrict__ gi, const float* __restrict__ G0,
    const int* __restrict__ p, const __bf16* __restrict__ gh,
    const float* __restrict__ bi, const float* __restrict__ bh,
    float* __restrict__ h, __bf16* __restrict__ hb)
{
    const int idx = blockIdx.x * 256 + threadIdx.x;   // (row, j/4)
    const int row = idx >> 7;
    const int j   = (idx & 127) << 2;
    if (row >= B_ROWS) return;
    const size_t gb = (size_t)row * GATE3;
    const size_t hbase = (size_t)row * HID + j;

    float ir[4], iz[4], inn[4];
    if (gi) {
        #pragma unroll
        for (int k = 0; k < 4; ++k) {
            ir[k]  = (float)gi[gb + j + k]            + bi[j + k];
            iz[k]  = (float)gi[gb + 512 + j + k]      + bi[512 + j + k];
            inn[k] = (float)gi[gb + 1024 + j + k]     + bi[1024 + j + k];
        }
    } else {
        const float* g = G0 + (size_t)p[row] * GATE3;
        #pragma unroll
        for (int k = 0; k < 4; ++k) {
            ir[k] = g[j + k]; iz[k] = g[512 + j + k]; inn[k] = g[1024 + j + k];
        }
    }
    float hr[4], hz[4], hn[4], hv[4];
    #pragma unroll
    for (int k = 0; k < 4; ++k) {
        hr[k] = (float)gh[gb + j + k]        + bh[j + k];
        hz[k] = (float)gh[gb + 512 + j + k]  + bh[512 + j + k];
        hn[k] = (float)gh[gb + 1024 + j + k] + bh[1024 + j + k];
        hv[k] = h[hbase + k];
    }
    #pragma unroll
    for (int k = 0; k < 4; ++k) {
        const float r = sig_(ir[k] + hr[k]);
        const float z = sig_(iz[k] + hz[k]);
        const float n = tanh_(inn[k] + r * hn[k]);
        const float o = (1.f - z) * n + z * hv[k];
        h[hbase + k]  = o;
        hb[hbase + k] = (__bf16)o;
    }
}

// ---------------------------------------------------------------------------
// logits = h1 @ w_out^T + b_out; log_softmax; argmax -> p; y stored fp32.
// One wave per row; lane = atom. w_out in XOR-swizzled LDS (64KB, no conflicts).
// ---------------------------------------------------------------------------
__device__ inline float bfbits_(uint32_t u) { return __builtin_bit_cast(float, u); }

__global__ __launch_bounds__(256) void out_step(
    const __bf16* __restrict__ h1b, const __bf16* __restrict__ woutb,
    const float* __restrict__ bout, float* __restrict__ y, int* __restrict__ p)
{
    __shared__ uint32_t wlds[ATOM * 256];   // 64 rows x 256 dwords (2 bf16 each)
    const int tid = threadIdx.x, lane = tid & 63, w = tid >> 6;

    const uint32_t* wsrc = (const uint32_t*)woutb;
    for (int r = 0; r < ATOM; ++r) {
        const int c = tid;                  // 256 dwords per row, 256 threads
        wlds[r * 256 + (c ^ (r & 31))] = wsrc[r * 256 + c];
    }
    __syncthreads();

    const float blog = bout[lane];
    const uint32_t* wrow = wlds + lane * 256;
    const int lx = lane & 31;
    const int row0 = blockIdx.x * 16 + w * 4;

    for (int rr = 0; rr < 4; ++rr) {
        const int row = row0 + rr;
        const uint32_t* hsrc = (const uint32_t*)(h1b + (size_t)row * HID);
        uint32_t hd[4];
        #pragma unroll
        for (int j = 0; j < 4; ++j) hd[j] = hsrc[lane * 4 + j];

        float s = 0.f;
        for (int kq = 0; kq < 64; ++kq) {
            #pragma unroll
            for (int j = 0; j < 4; ++j) {
                const int k2 = kq * 4 + j;
                const uint32_t hv = (uint32_t)__shfl((int)hd[j], kq, 64);
                const uint32_t wv = wrow[k2 ^ lx];
                s += bfbits_(hv << 16) * bfbits_(wv << 16)
                   + bfbits_(hv & 0xffff0000u) * bfbits_(wv & 0xffff0000u);
            }
        }
        const float logit = s + blog;

        float mval = logit; int midx = lane;
        #pragma unroll
        for (int off = 32; off >= 1; off >>= 1) {
            const float ov = __shfl_xor(mval, off, 64);
            const int   oi = __shfl_xor(midx, off, 64);
            if (ov > mval || (ov == mval && oi < midx)) { mval = ov; midx = oi; }
        }
        float se = expf(logit - mval);
        #pragma unroll
        for (int off = 32; off >= 1; off >>= 1) se += __shfl_xor(se, off, 64);
        const float yv = logit - mval - logf(se);

        y[(size_t)row * ATOM + lane] = yv;
        if (lane == 0) p[row] = midx;
    }
}

// ---------------------------------------------------------------------------
// helpers: fp32 -> bf16 convert; G0 precompute; p init
// ---------------------------------------------------------------------------
__global__ __launch_bounds__(256) void f2b(const float* __restrict__ s,
                                           __bf16* __restrict__ d, int n)
{
    const int i = (blockIdx.x * 256 + threadIdx.x) * 4;
    if (i + 3 < n) {
        const float4 v = *(const float4*)(s + i);
        bf16x4 o = { (__bf16)v.x, (__bf16)v.y, (__bf16)v.z, (__bf16)v.w };
        *(bf16x4*)(d + i) = o;
    }
}

__global__ __launch_bounds__(256) void g0k(const float* __restrict__ emb,
                                           const float* __restrict__ wih0,
                                           const float* __restrict__ bih0,
                                           float* __restrict__ G0)
{
    const int i = blockIdx.x * 256 + threadIdx.x;   // 64*1536
    if (i >= ATOM * GATE3) return;
    const int a = i / GATE3, c = i % GATE3;
    float s = bih0[c];
    for (int k = 0; k < 50; ++k) s += emb[a * 50 + k] * wih0[c * 50 + k];
    G0[i] = s;
}

__global__ __launch_bounds__(256) void initp(int* __restrict__ p)
{
    const int i = blockIdx.x * 256 + threadIdx.x;
    if (i < B_ROWS) p[i] = 1;   // SOS = 1
}

// ---------------------------------------------------------------------------
extern "C" void kernel_launch(void* const* d_in, const int* in_sizes, int n_in,
                              void* d_out, int out_size, void* d_ws, size_t ws_size,
                              hipStream_t stream)
{
    (void)in_sizes; (void)n_in; (void)out_size; (void)ws_size;
    const float* enc   = (const float*)d_in[0];
    const float* emb   = (const float*)d_in[1];
    const float* w_h0  = (const float*)d_in[2];
    const float* b_h0  = (const float*)d_in[3];
    const float* w_ih0 = (const float*)d_in[4];
    const float* w_hh0 = (const float*)d_in[5];
    const float* b_ih0 = (const float*)d_in[6];
    const float* b_hh0 = (const float*)d_in[7];
    const float* w_ih1 = (const float*)d_in[8];
    const float* w_hh1 = (const float*)d_in[9];
    const float* b_ih1 = (const float*)d_in[10];
    const float* b_hh1 = (const float*)d_in[11];
    const float* w_out = (const float*)d_in[12];
    const float* b_out = (const float*)d_in[13];
    float* out = (float*)d_out;

    char* ws = (char*)d_ws;
    size_t off = 0;
    auto alloc = [&](size_t bytes) -> void* {
        void* pp = ws + off;
        off = (off + bytes + 255) & ~(size_t)255;
        return pp;
    };
    __bf16* whh0_b = (__bf16*)alloc((size_t)GATE3 * HID * 2);
    __bf16* wih1_b = (__bf16*)alloc((size_t)GATE3 * HID * 2);
    __bf16* whh1_b = (__bf16*)alloc((size_t)GATE3 * HID * 2);
    __bf16* wout_b = (__bf16*)alloc((size_t)ATOM * HID * 2);
    float*  G0     = (float*) alloc((size_t)ATOM * GATE3 * 4);
    float*  h0f    = (float*) alloc((size_t)B_ROWS * HID * 4);
    __bf16* h0b    = (__bf16*)alloc((size_t)B_ROWS * HID * 2);
    float*  h1f    = (float*) alloc((size_t)B_ROWS * HID * 4);
    __bf16* h1b    = (__bf16*)alloc((size_t)B_ROWS * HID * 2);
    int*    p      = (int*)   alloc((size_t)B_ROWS * 4);
    __bf16* ghA    = (__bf16*)alloc((size_t)B_ROWS * GATE3 * 2);  // gh0, then gi1
    const size_t mark = off;
    __bf16* gh1    = (__bf16*)alloc((size_t)B_ROWS * GATE3 * 2);
    const size_t endA = off;
    off = mark;                       // init-only buffers alias gh1's region
    __bf16* enc_b  = (__bf16*)alloc((size_t)B_ROWS * 1024 * 2);
    __bf16* wh0_b  = (__bf16*)alloc((size_t)1024 * 1024 * 2);
    if (off < endA) off = endA;

    // ---- once-per-launch prep ----
    f2b<<<8192, 256, 0, stream>>>(enc,   enc_b,  B_ROWS * 1024);
    f2b<<<1024, 256, 0, stream>>>(w_h0,  wh0_b,  1024 * 1024);
    f2b<<<768,  256, 0, stream>>>(w_hh0, whh0_b, GATE3 * HID);
    f2b<<<768,  256, 0, stream>>>(w_ih1, wih1_b, GATE3 * HID);
    f2b<<<768,  256, 0, stream>>>(w_hh1, whh1_b, GATE3 * HID);
    f2b<<<32,   256, 0, stream>>>(w_out, wout_b, ATOM * HID);
    g0k<<<384, 256, 0, stream>>>(emb, w_ih0, b_ih0, G0);
    initp<<<32, 256, 0, stream>>>(p);

    // init: h = tanh(enc @ w_h0^T + b_h0) -> h0 | h1
    gemm_bt<<<dim3(B_ROWS / BM, 1024 / BN), 256, 0, stream>>>(
        enc_b, wh0_b, B_ROWS, 1024, 1024, 1, b_h0,
        nullptr, h0f, h0b, h1f, h1b);

    // ---- 49 decode steps ----
    for (int step = 0; step < NSTEP; ++step) {
        // gh0 = h0 @ w_hh0^T
        gemm_bt<<<dim3(B_ROWS / BM, GATE3 / BN), 256, 0, stream>>>(
            h0b, whh0_b, B_ROWS, GATE3, HID, 0, nullptr,
            ghA, nullptr, nullptr, nullptr, nullptr);
        // h0 = GRU0(G0[p], gh0, h0)
        gru_gate<<<4096, 256, 0, stream>>>(nullptr, G0, p, ghA,
                                           nullptr, b_hh0, h0f, h0b);
        // gi1 = h0 @ w_ih1^T (reuses ghA), gh1 = h1 @ w_hh1^T
        gemm_bt<<<dim3(B_ROWS / BM, GATE3 / BN), 256, 0, stream>>>(
            h0b, wih1_b, B_ROWS, GATE3, HID, 0, nullptr,
            ghA, nullptr, nullptr, nullptr, nullptr);
        gemm_bt<<<dim3(B_ROWS / BM, GATE3 / BN), 256, 0, stream>>>(
            h1b, whh1_b, B_ROWS, GATE3, HID, 0, nullptr,
            gh1, nullptr, nullptr, nullptr, nullptr);
        // h1 = GRU1(gi1, gh1, h1)
        gru_gate<<<4096, 256, 0, stream>>>(ghA, nullptr, nullptr, gh1,
                                           b_ih1, b_hh1, h1f, h1b);
        // y[step], p = log_softmax/argmax(h1 @ w_out^T + b_out)
        out_step<<<512, 256, 0, stream>>>(h1b, wout_b, b_out,
                                          out + (size_t)step * B_ROWS * ATOM, p);
    }
}

// Round 2
// 6300.890 us; speedup vs baseline: 1.1668x; 1.1668x over previous
//
#include <hip/hip_runtime.h>
#include <hip/hip_bf16.h>
#include <cstdint>
#include <cstddef>

// ---------------------------------------------------------------------------
// 2-layer GRU decoder. B=8192, H=512, ENC=1024, ATOM=64, 49 steps.
// Gate-permuted weights: q = 48*(j/16) + 16*g + (j%16)  <->  orig row g*512+j,
// so a 48-col wave strip holds gates r,z,n for 16 h-units at matching lanes.
// GRU update fused into GEMM epilogue (fp32 gh, never rounded).
// ---------------------------------------------------------------------------

typedef __attribute__((ext_vector_type(8))) __bf16 bf16x8;
typedef __attribute__((ext_vector_type(4))) __bf16 bf16x4;
typedef __attribute__((ext_vector_type(4))) float f32x4;

#define B_ROWS 8192
#define HID 512
#define GATE3 1536
#define ATOM 64
#define NSTEP 49

#define GLOAD_LDS16(gp, sp)                                                   \
  __builtin_amdgcn_global_load_lds(                                           \
      (__attribute__((address_space(1))) void*)(gp),                          \
      (__attribute__((address_space(3))) void*)(sp), 16, 0, 0)

__device__ inline float sig_(float x) { return 1.f / (1.f + __expf(-x)); }
__device__ inline float tanh_(float x) { return 2.f / (1.f + __expf(-2.f * x)) - 1.f; }

// ---------------------------------------------------------------------------
// Fused GRU GEMM: acc = A[8192,512] @ Bp[1536,512]^T (Bp gate-permuted).
// mode 0: store bf16 C (permuted layout) -> Cout
// mode 1: layer0 — gi = G0p[p[row]] (b_ih folded), gate update h
// mode 2: layer1 — gi = giBuf (bf16, permuted) + bi_p, gate update h
// BM=64, BN=192 (4 waves x 48-col triple), BK=32.
// ---------------------------------------------------------------------------
__global__ __launch_bounds__(256) void gemm_gru(
    const __bf16* __restrict__ A, const __bf16* __restrict__ Bp, int mode,
    __bf16* __restrict__ Cout,
    const float* __restrict__ G0p, const int* __restrict__ p,
    const __bf16* __restrict__ giBuf, const float* __restrict__ bi_p,
    const float* __restrict__ bh_p,
    const float* __restrict__ hprev, float* __restrict__ hnewf,
    __bf16* __restrict__ hnewb)
{
    __shared__ __bf16 As[64 * 32];    // 4 KB
    __shared__ __bf16 Bs[192 * 32];   // 12 KB

    const int tid  = threadIdx.x;
    const int lane = tid & 63;
    const int w    = tid >> 6;
    const int m0   = blockIdx.x * 64;
    const int n0   = blockIdx.y * 192;

    f32x4 acc[4][3] = {};

    // staging: A 256 chunks (16B), B 768 chunks; thread -> 1 A + 3 B chunks
    const __bf16* Ap  = A  + (size_t)(m0 + (tid >> 2)) * HID + (tid & 3) * 8;
    const __bf16* Bg0 = Bp + (size_t)(n0 + (tid >> 2)) * HID + (tid & 3) * 8;
    const __bf16* Bg1 = Bg0 + (size_t)64  * HID;
    const __bf16* Bg2 = Bg0 + (size_t)128 * HID;
    __bf16* AsW  = As + w * 512;
    __bf16* BsW0 = Bs + w * 512;
    __bf16* BsW1 = Bs + 2048 + w * 512;
    __bf16* BsW2 = Bs + 4096 + w * 512;

    const int u    = lane & 15;
    const int koff = (lane >> 4) * 8;

    for (int kt = 0; kt < HID / 32; ++kt) {
        __syncthreads();
        GLOAD_LDS16(Ap,  AsW);
        GLOAD_LDS16(Bg0, BsW0);
        GLOAD_LDS16(Bg1, BsW1);
        GLOAD_LDS16(Bg2, BsW2);
        Ap += 32; Bg0 += 32; Bg1 += 32; Bg2 += 32;
        __syncthreads();

        bf16x8 af[4], bfr[3];
        #pragma unroll
        for (int mf = 0; mf < 4; ++mf)
            af[mf] = *(const bf16x8*)&As[(mf * 16 + u) * 32 + koff];
        #pragma unroll
        for (int g = 0; g < 3; ++g)
            bfr[g] = *(const bf16x8*)&Bs[(w * 48 + g * 16 + u) * 32 + koff];
        #pragma unroll
        for (int mf = 0; mf < 4; ++mf)
            #pragma unroll
            for (int g = 0; g < 3; ++g)
                acc[mf][g] = __builtin_amdgcn_mfma_f32_16x16x32_bf16(
                    af[mf], bfr[g], acc[mf][g], 0, 0, 0);
    }

    // epilogue: row = m0 + mf*16 + (lane>>4)*4 + r ; wave triple t covers
    // h-units j = t*16+u, gate g at permuted col qb + 16g, qb = t*48+u.
    const int t  = blockIdx.y * 4 + w;
    const int j  = t * 16 + u;
    const int qb = t * 48 + u;

    if (mode == 0) {
        #pragma unroll
        for (int mf = 0; mf < 4; ++mf)
            #pragma unroll
            for (int r = 0; r < 4; ++r) {
                const int row = m0 + mf * 16 + ((lane >> 4) << 2) + r;
                #pragma unroll
                for (int g = 0; g < 3; ++g)
                    Cout[(size_t)row * GATE3 + n0 + w * 48 + g * 16 + u] =
                        (__bf16)acc[mf][g][r];
            }
        return;
    }

    const float bhr = bh_p[qb], bhz = bh_p[qb + 16], bhn = bh_p[qb + 32];
    float bir = 0.f, biz = 0.f, bin = 0.f;
    if (mode == 2) { bir = bi_p[qb]; biz = bi_p[qb + 16]; bin = bi_p[qb + 32]; }

    #pragma unroll
    for (int mf = 0; mf < 4; ++mf) {
        #pragma unroll
        for (int r = 0; r < 4; ++r) {
            const int row = m0 + mf * 16 + ((lane >> 4) << 2) + r;
            float gir, giz, gin;
            if (mode == 1) {
                const float* g0 = G0p + (size_t)p[row] * GATE3 + qb;
                gir = g0[0]; giz = g0[16]; gin = g0[32];
            } else {
                const __bf16* gi = giBuf + (size_t)row * GATE3 + qb;
                gir = (float)gi[0]  + bir;
                giz = (float)gi[16] + biz;
                gin = (float)gi[32] + bin;
            }
            const float rr = sig_(gir + acc[mf][0][r] + bhr);
            const float zz = sig_(giz + acc[mf][1][r] + bhz);
            const float nn = tanh_(gin + rr * (acc[mf][2][r] + bhn));
            const float hp = hprev[(size_t)row * HID + j];
            const float hv = (1.f - zz) * nn + zz * hp;
            hnewf[(size_t)row * HID + j] = hv;
            hnewb[(size_t)row * HID + j] = (__bf16)hv;
        }
    }
}

// ---------------------------------------------------------------------------
// out: logits = h1 @ w_out^T + b_out (MFMA, BM=64, N=64, K=512);
// log_softmax + argmax fused. wave w -> rows w*16..; cols nf*16+u.
// ---------------------------------------------------------------------------
__global__ __launch_bounds__(256) void out_mfma(
    const __bf16* __restrict__ h1b, const __bf16* __restrict__ woutb,
    const float* __restrict__ bout, float* __restrict__ y, int* __restrict__ p)
{
    __shared__ __bf16 As[64 * 32];
    __shared__ __bf16 Bs[64 * 32];

    const int tid  = threadIdx.x;
    const int lane = tid & 63;
    const int w    = tid >> 6;
    const int m0   = blockIdx.x * 64;

    f32x4 acc[4] = {};

    const __bf16* Ap = h1b  + (size_t)(m0 + (tid >> 2)) * HID + (tid & 3) * 8;
    const __bf16* Wp = woutb + (size_t)(tid >> 2) * HID + (tid & 3) * 8;
    __bf16* AsW = As + w * 512;
    __bf16* BsW = Bs + w * 512;

    const int u    = lane & 15;
    const int koff = (lane >> 4) * 8;

    for (int kt = 0; kt < HID / 32; ++kt) {
        __syncthreads();
        GLOAD_LDS16(Ap, AsW);
        GLOAD_LDS16(Wp, BsW);
        Ap += 32; Wp += 32;
        __syncthreads();

        const bf16x8 af = *(const bf16x8*)&As[(w * 16 + u) * 32 + koff];
        #pragma unroll
        for (int nf = 0; nf < 4; ++nf) {
            const bf16x8 bfr = *(const bf16x8*)&Bs[(nf * 16 + u) * 32 + koff];
            acc[nf] = __builtin_amdgcn_mfma_f32_16x16x32_bf16(af, bfr, acc[nf], 0, 0, 0);
        }
    }

    #pragma unroll
    for (int r = 0; r < 4; ++r) {
        const int row = m0 + w * 16 + ((lane >> 4) << 2) + r;
        float l[4];
        #pragma unroll
        for (int nf = 0; nf < 4; ++nf) l[nf] = acc[nf][r] + bout[nf * 16 + u];

        float mv = l[0]; int mi = u;
        #pragma unroll
        for (int nf = 1; nf < 4; ++nf)
            if (l[nf] > mv) { mv = l[nf]; mi = nf * 16 + u; }
        #pragma unroll
        for (int off = 1; off <= 8; off <<= 1) {
            const float ov = __shfl_xor(mv, off, 64);
            const int   oi = __shfl_xor(mi, off, 64);
            if (ov > mv || (ov == mv && oi < mi)) { mv = ov; mi = oi; }
        }
        float se = 0.f;
        #pragma unroll
        for (int nf = 0; nf < 4; ++nf) se += __expf(l[nf] - mv);
        #pragma unroll
        for (int off = 1; off <= 8; off <<= 1) se += __shfl_xor(se, off, 64);
        const float lse = logf(se);

        #pragma unroll
        for (int nf = 0; nf < 4; ++nf)
            y[(size_t)row * ATOM + nf * 16 + u] = l[nf] - mv - lse;
        if (u == 0) p[row] = mi;
    }
}

// ---------------------------------------------------------------------------
// Init GEMM (enc -> h): BM=BN=128, BK=32, tanh epilogue splitting h0|h1.
// ---------------------------------------------------------------------------
__global__ __launch_bounds__(256) void gemm_init(
    const __bf16* __restrict__ A, const __bf16* __restrict__ B,
    int N, int K, const float* __restrict__ bias,
    float* __restrict__ H0f, __bf16* __restrict__ H0b,
    float* __restrict__ H1f, __bf16* __restrict__ H1b)
{
    __shared__ __bf16 As[128 * 32];
    __shared__ __bf16 Bs[128 * 32];

    const int tid  = threadIdx.x;
    const int lane = tid & 63;
    const int w    = tid >> 6;
    const int wm   = w >> 1, wn = w & 1;
    const int m0   = blockIdx.x * 128;
    const int n0   = blockIdx.y * 128;

    f32x4 acc[4][4] = {};

    const int i0 = w * 64 + lane;
    const int i1 = i0 + 256;
    const __bf16* Ap0 = A + (size_t)(m0 + (i0 >> 2)) * K + (i0 & 3) * 8;
    const __bf16* Ap1 = A + (size_t)(m0 + (i1 >> 2)) * K + (i1 & 3) * 8;
    const __bf16* Bp0 = B + (size_t)(n0 + (i0 >> 2)) * K + (i0 & 3) * 8;
    const __bf16* Bp1 = B + (size_t)(n0 + (i1 >> 2)) * K + (i1 & 3) * 8;
    __bf16* As0 = As + w * 512;
    __bf16* As1 = As + 2048 + w * 512;
    __bf16* Bs0 = Bs + w * 512;
    __bf16* Bs1 = Bs + 2048 + w * 512;

    const int mrow = wm * 64 + (lane & 15);
    const int nrow = wn * 64 + (lane & 15);
    const int koff = (lane >> 4) * 8;

    for (int kt = 0; kt < K / 32; ++kt) {
        __syncthreads();
        GLOAD_LDS16(Ap0, As0);
        GLOAD_LDS16(Ap1, As1);
        GLOAD_LDS16(Bp0, Bs0);
        GLOAD_LDS16(Bp1, Bs1);
        Ap0 += 32; Ap1 += 32; Bp0 += 32; Bp1 += 32;
        __syncthreads();

        bf16x8 af[4], bfr[4];
        #pragma unroll
        for (int f = 0; f < 4; ++f) {
            af[f]  = *(const bf16x8*)&As[(mrow + f * 16) * 32 + koff];
            bfr[f] = *(const bf16x8*)&Bs[(nrow + f * 16) * 32 + koff];
        }
        #pragma unroll
        for (int mf = 0; mf < 4; ++mf)
            #pragma unroll
            for (int nf = 0; nf < 4; ++nf)
                acc[mf][nf] = __builtin_amdgcn_mfma_f32_16x16x32_bf16(
                    af[mf], bfr[nf], acc[mf][nf], 0, 0, 0);
    }

    const int colb = n0 + wn * 64 + (lane & 15);
    const int rowb = m0 + wm * 64 + ((lane >> 4) << 2);
    #pragma unroll
    for (int mf = 0; mf < 4; ++mf)
        #pragma unroll
        for (int nf = 0; nf < 4; ++nf) {
            const int col = colb + nf * 16;
            #pragma unroll
            for (int r = 0; r < 4; ++r) {
                const int row = rowb + mf * 16 + r;
                const float v = tanhf(acc[mf][nf][r] + bias[col]);
                if (col < HID) {
                    H0f[(size_t)row * HID + col] = v;
                    H0b[(size_t)row * HID + col] = (__bf16)v;
                } else {
                    H1f[(size_t)row * HID + col - HID] = v;
                    H1b[(size_t)row * HID + col - HID] = (__bf16)v;
                }
            }
        }
}

// ---------------------------------------------------------------------------
// prep kernels
// ---------------------------------------------------------------------------
__device__ inline int permQ(int q) {          // permuted q -> original row
    const int t = q / 48, rem = q % 48;
    return (rem / 16) * HID + t * 16 + (rem % 16);
}

__global__ __launch_bounds__(256) void f2b(const float* __restrict__ s,
                                           __bf16* __restrict__ d, int n)
{
    const int i = (blockIdx.x * 256 + threadIdx.x) * 4;
    if (i + 3 < n) {
        const float4 v = *(const float4*)(s + i);
        bf16x4 o = { (__bf16)v.x, (__bf16)v.y, (__bf16)v.z, (__bf16)v.w };
        *(bf16x4*)(d + i) = o;
    }
}

__global__ __launch_bounds__(256) void f2bp(const float* __restrict__ s,
                                            __bf16* __restrict__ d)
{
    const int idx = blockIdx.x * 256 + threadIdx.x;   // 1536*128
    const int q = idx >> 7, k = (idx & 127) << 2;
    const int o = permQ(q);
    const float4 v = *(const float4*)(s + (size_t)o * HID + k);
    bf16x4 ov = { (__bf16)v.x, (__bf16)v.y, (__bf16)v.z, (__bf16)v.w };
    *(bf16x4*)(d + (size_t)q * HID + k) = ov;
}

__global__ __launch_bounds__(256) void bperm(const float* __restrict__ s,
                                             float* __restrict__ d)
{
    const int q = blockIdx.x * 256 + threadIdx.x;
    if (q < GATE3) d[q] = s[permQ(q)];
}

__global__ __launch_bounds__(256) void g0pk(const float* __restrict__ emb,
                                            const float* __restrict__ wih0,
                                            const float* __restrict__ bih0,
                                            float* __restrict__ G0p)
{
    const int i = blockIdx.x * 256 + threadIdx.x;   // 64*1536
    if (i >= ATOM * GATE3) return;
    const int a = i / GATE3, q = i % GATE3;
    const int o = permQ(q);
    float s = bih0[o];
    for (int k = 0; k < 50; ++k) s += emb[a * 50 + k] * wih0[o * 50 + k];
    G0p[i] = s;
}

__global__ __launch_bounds__(256) void initp(int* __restrict__ p)
{
    const int i = blockIdx.x * 256 + threadIdx.x;
    if (i < B_ROWS) p[i] = 1;   // SOS
}

// ---------------------------------------------------------------------------
extern "C" void kernel_launch(void* const* d_in, const int* in_sizes, int n_in,
                              void* d_out, int out_size, void* d_ws, size_t ws_size,
                              hipStream_t stream)
{
    (void)in_sizes; (void)n_in; (void)out_size; (void)ws_size;
    const float* enc   = (const float*)d_in[0];
    const float* emb   = (const float*)d_in[1];
    const float* w_h0  = (const float*)d_in[2];
    const float* b_h0  = (const float*)d_in[3];
    const float* w_ih0 = (const float*)d_in[4];
    const float* w_hh0 = (const float*)d_in[5];
    const float* b_ih0 = (const float*)d_in[6];
    const float* b_hh0 = (const float*)d_in[7];
    const float* w_ih1 = (const float*)d_in[8];
    const float* w_hh1 = (const float*)d_in[9];
    const float* b_ih1 = (const float*)d_in[10];
    const float* b_hh1 = (const float*)d_in[11];
    const float* w_out = (const float*)d_in[12];
    const float* b_out = (const float*)d_in[13];
    float* out = (float*)d_out;

    char* ws = (char*)d_ws;
    size_t off = 0;
    auto alloc = [&](size_t bytes) -> void* {
        void* pp = ws + off;
        off = (off + bytes + 255) & ~(size_t)255;
        return pp;
    };
    __bf16* whh0p = (__bf16*)alloc((size_t)GATE3 * HID * 2);
    __bf16* wih1p = (__bf16*)alloc((size_t)GATE3 * HID * 2);
    __bf16* whh1p = (__bf16*)alloc((size_t)GATE3 * HID * 2);
    __bf16* woutb = (__bf16*)alloc((size_t)ATOM * HID * 2);
    float*  G0p   = (float*) alloc((size_t)ATOM * GATE3 * 4);
    float*  bhh0p = (float*) alloc(GATE3 * 4);
    float*  bih1p = (float*) alloc(GATE3 * 4);
    float*  bhh1p = (float*) alloc(GATE3 * 4);
    float*  h0f[2]; __bf16* h0b[2]; float* h1f[2]; __bf16* h1b[2];
    for (int i = 0; i < 2; ++i) {
        h0f[i] = (float*) alloc((size_t)B_ROWS * HID * 4);
        h0b[i] = (__bf16*)alloc((size_t)B_ROWS * HID * 2);
        h1f[i] = (float*) alloc((size_t)B_ROWS * HID * 4);
        h1b[i] = (__bf16*)alloc((size_t)B_ROWS * HID * 2);
    }
    int* p = (int*)alloc((size_t)B_ROWS * 4);
    const size_t mark = off;
    __bf16* gi1   = (__bf16*)alloc((size_t)B_ROWS * GATE3 * 2);   // step-only
    const size_t endA = off;
    off = mark;                        // init-only buffers alias gi1
    __bf16* enc_b = (__bf16*)alloc((size_t)B_ROWS * 1024 * 2);
    __bf16* wh0b  = (__bf16*)alloc((size_t)1024 * 1024 * 2);
    if (off < endA) off = endA;

    // ---- prep ----
    f2b <<<8192, 256, 0, stream>>>(enc,  enc_b, B_ROWS * 1024);
    f2b <<<1024, 256, 0, stream>>>(w_h0, wh0b,  1024 * 1024);
    f2b <<<32,   256, 0, stream>>>(w_out, woutb, ATOM * HID);
    f2bp<<<768,  256, 0, stream>>>(w_hh0, whh0p);
    f2bp<<<768,  256, 0, stream>>>(w_ih1, wih1p);
    f2bp<<<768,  256, 0, stream>>>(w_hh1, whh1p);
    bperm<<<6, 256, 0, stream>>>(b_hh0, bhh0p);
    bperm<<<6, 256, 0, stream>>>(b_ih1, bih1p);
    bperm<<<6, 256, 0, stream>>>(b_hh1, bhh1p);
    g0pk<<<384, 256, 0, stream>>>(emb, w_ih0, b_ih0, G0p);
    initp<<<32, 256, 0, stream>>>(p);

    gemm_init<<<dim3(B_ROWS / 128, 1024 / 128), 256, 0, stream>>>(
        enc_b, wh0b, 1024, 1024, b_h0, h0f[0], h0b[0], h1f[0], h1b[0]);

    // ---- 49 decode steps ----
    const dim3 gGrid(B_ROWS / 64, GATE3 / 192);
    for (int step = 0; step < NSTEP; ++step) {
        const int cur = step & 1, nxt = cur ^ 1;
        // layer0: gh0 GEMM + fused GRU update (gi from G0p[p])
        gemm_gru<<<gGrid, 256, 0, stream>>>(
            h0b[cur], whh0p, 1, nullptr, G0p, p, nullptr, nullptr,
            bhh0p, h0f[cur], h0f[nxt], h0b[nxt]);
        // gi1 = h0_new @ w_ih1p^T (plain store, permuted bf16)
        gemm_gru<<<gGrid, 256, 0, stream>>>(
            h0b[nxt], wih1p, 0, gi1, nullptr, nullptr, nullptr, nullptr,
            nullptr, nullptr, nullptr, nullptr);
        // layer1: gh1 GEMM + fused GRU update (gi from gi1 buffer)
        gemm_gru<<<gGrid, 256, 0, stream>>>(
            h1b[cur], whh1p, 2, nullptr, nullptr, nullptr, gi1, bih1p,
            bhh1p, h1f[cur], h1f[nxt], h1b[nxt]);
        // y[step], p = log_softmax/argmax(h1_new @ w_out^T + b_out)
        out_mfma<<<B_ROWS / 64, 256, 0, stream>>>(
            h1b[nxt], woutb, b_out,
            out + (size_t)step * B_ROWS * ATOM, p);
    }
}